// Round 1
// baseline (480.784 us; speedup 1.0000x reference)
//
#include <hip/hip_runtime.h>
#include <hip/hip_fp16.h>

#define B_ 16
#define XL_ 1024
#define KL_ 512
#define D_ 1024
#define NEGC (-10000000.0f)

typedef _Float16 f16x8 __attribute__((ext_vector_type(8)));
typedef float f32x4 __attribute__((ext_vector_type(4)));
typedef unsigned short u16x8 __attribute__((ext_vector_type(8)));
typedef unsigned short u16x4 __attribute__((ext_vector_type(4)));

__device__ __forceinline__ unsigned short f2h(float f) {
  __half h = __float2half(f);
  return __half_as_ushort(h);
}

// ---------- prep: x_logits = x . w_input (wave per row) ----------
__global__ __launch_bounds__(256) void k_prep_x(const float* __restrict__ x,
    const float* __restrict__ w_input, float* __restrict__ xlog) {
  int wv = threadIdx.x >> 6, lane = threadIdx.x & 63;
  int row = blockIdx.x * 4 + wv;
  const float* src = x + (size_t)row * D_;
  float acc = 0.f;
#pragma unroll
  for (int j = 0; j < 4; ++j) {
    int d = j * 256 + lane * 4;
    float4 v = *(const float4*)(src + d);
    float4 w = *(const float4*)(w_input + d);
    acc += v.x * w.x + v.y * w.y + v.z * w.z + v.w * w.w;
  }
#pragma unroll
  for (int sh = 32; sh >= 1; sh >>= 1) acc += __shfl_xor(acc, sh);
  if (lane == 0) xlog[row] = acc;
}

// ---------- prep: key -> fp16 Kh, key_logits = key . w_key ----------
__global__ __launch_bounds__(256) void k_prep_key(const float* __restrict__ key,
    const float* __restrict__ w_key, unsigned short* __restrict__ Kh,
    float* __restrict__ klog) {
  int wv = threadIdx.x >> 6, lane = threadIdx.x & 63;
  int row = blockIdx.x * 4 + wv;
  const float* src = key + (size_t)row * D_;
  unsigned short* dst = Kh + (size_t)row * D_;
  float acc = 0.f;
#pragma unroll
  for (int j = 0; j < 4; ++j) {
    int d = j * 256 + lane * 4;
    float4 v = *(const float4*)(src + d);
    float4 w = *(const float4*)(w_key + d);
    acc += v.x * w.x + v.y * w.y + v.z * w.z + v.w * w.w;
    u16x4 hv;
    hv[0] = f2h(v.x); hv[1] = f2h(v.y); hv[2] = f2h(v.z); hv[3] = f2h(v.w);
    *(u16x4*)(dst + d) = hv;
  }
#pragma unroll
  for (int sh = 32; sh >= 1; sh >>= 1) acc += __shfl_xor(acc, sh);
  if (lane == 0) klog[row] = acc;
}

// ---------- transpose Kh [b][k][d] -> KhT [b][d][k] (64x64 tiles) ----------
__global__ __launch_bounds__(256) void k_transpose(const unsigned short* __restrict__ Kh,
    unsigned short* __restrict__ KhT) {
  __shared__ unsigned short tile[64][72];
  int bid = blockIdx.x;
  int b = bid >> 7; int rem = bid & 127; int kt = rem >> 4; int dt = rem & 15;
  const unsigned short* src = Kh + ((size_t)b * KL_ + kt * 64) * D_ + dt * 64;
  int tr = threadIdx.x >> 3, tc = (threadIdx.x & 7) * 8;
#pragma unroll
  for (int i = 0; i < 2; ++i) {
    int r = i * 32 + tr;
    u16x8 v = *(const u16x8*)(src + (size_t)r * D_ + tc);
    *(u16x8*)(&tile[r][tc]) = v;
  }
  __syncthreads();
  unsigned short* dst = KhT + ((size_t)b * D_ + dt * 64) * KL_ + kt * 64;
#pragma unroll
  for (int i = 0; i < 2; ++i) {
    int dr = i * 32 + tr;
    u16x8 v;
#pragma unroll
    for (int j = 0; j < 8; ++j) v[j] = tile[tc + j][dr];
    *(u16x8*)(dst + (size_t)dr * KL_ + tc) = v;
  }
}

// ---------- main attention kernel ----------
// Block: 256 thr (4 waves). Tile: 32 x-rows x KL=512 (wave w owns cols w*128..+128).
// Phase 1: S = (x*dot_w) @ key^T via mfma 16x16x32 f16, K-frags direct from L2.
// Then 2-pass softmax (joint-mask) + max_s (key-mask), P->LDS fp16 (XOR swizzle).
// Phase 2: x2key = P @ key via KhT; write out[.,D:2D)=x2key, out[.,2D:3D)=x*x2key.
__global__ __launch_bounds__(256) void k_attn(
    const float* __restrict__ x, const float* __restrict__ x_mask,
    const float* __restrict__ key_mask, const float* __restrict__ dot_w,
    const unsigned short* __restrict__ Kh, const unsigned short* __restrict__ KhT,
    const float* __restrict__ xlog, const float* __restrict__ klog,
    float* __restrict__ maxs, float* __restrict__ out) {
  __shared__ unsigned short Pt[32 * 512];   // 32KB: P matrix (phase 2), XOR-swizzled
  __shared__ unsigned short Qt[32][136];    // 8.7KB: Q chunk [32][128], padded
  __shared__ float redA[4][32], redB[4][32], redC[4][32];

  const int tid = threadIdx.x;
  const int wv = tid >> 6;
  const int lane = tid & 63;
  const int l15 = lane & 15, l4 = lane >> 4;

  // XCD-aware swizzle: 512 blocks, XCD = bid&7 gets batches {2x, 2x+1}
  int bid = blockIdx.x;
  int b = (bid & 7) * 2 + (bid >> 8);
  int x0 = ((bid >> 3) & 31) * 32;

  const unsigned short* KhB = Kh + (size_t)b * KL_ * D_;
  const float* xB = x + ((size_t)b * XL_ + x0) * D_;

  f32x4 acc[2][8];
#pragma unroll
  for (int m = 0; m < 2; ++m)
#pragma unroll
    for (int n = 0; n < 8; ++n) { f32x4 z = {0.f, 0.f, 0.f, 0.f}; acc[m][n] = z; }

  // per-wave B-fragment base pointers (8 columns of S = 8 key rows per frag set)
  const unsigned short* bp[8];
#pragma unroll
  for (int n = 0; n < 8; ++n) {
    int kr = wv * 128 + n * 16 + l15;
    bp[n] = KhB + (size_t)kr * D_ + l4 * 8;
  }

  for (int dk0 = 0; dk0 < D_; dk0 += 128) {
    // stage Q chunk [32][128] fp16 = x*dot_w
    {
      int r = tid >> 3;
      int c = (tid & 7) * 16;
      const float* sp = xB + (size_t)r * D_ + dk0 + c;
      const float* wp = dot_w + dk0 + c;
      float4 v0 = *(const float4*)(sp);
      float4 v1 = *(const float4*)(sp + 4);
      float4 v2 = *(const float4*)(sp + 8);
      float4 v3 = *(const float4*)(sp + 12);
      float4 w0 = *(const float4*)(wp);
      float4 w1 = *(const float4*)(wp + 4);
      float4 w2 = *(const float4*)(wp + 8);
      float4 w3 = *(const float4*)(wp + 12);
      u16x8 h0, h1;
      h0[0] = f2h(v0.x * w0.x); h0[1] = f2h(v0.y * w0.y);
      h0[2] = f2h(v0.z * w0.z); h0[3] = f2h(v0.w * w0.w);
      h0[4] = f2h(v1.x * w1.x); h0[5] = f2h(v1.y * w1.y);
      h0[6] = f2h(v1.z * w1.z); h0[7] = f2h(v1.w * w1.w);
      h1[0] = f2h(v2.x * w2.x); h1[1] = f2h(v2.y * w2.y);
      h1[2] = f2h(v2.z * w2.z); h1[3] = f2h(v2.w * w2.w);
      h1[4] = f2h(v3.x * w3.x); h1[5] = f2h(v3.y * w3.y);
      h1[6] = f2h(v3.z * w3.z); h1[7] = f2h(v3.w * w3.w);
      *(u16x8*)(&Qt[r][c]) = h0;
      *(u16x8*)(&Qt[r][c + 8]) = h1;
    }
    __syncthreads();
#pragma unroll
    for (int dd = 0; dd < 128; dd += 32) {
      f16x8 a0 = *(const f16x8*)(&Qt[l15][dd + l4 * 8]);
      f16x8 a1 = *(const f16x8*)(&Qt[16 + l15][dd + l4 * 8]);
      int go = dk0 + dd;
#pragma unroll
      for (int n = 0; n < 8; ++n) {
        f16x8 bf = *(const f16x8*)(bp[n] + go);
        acc[0][n] = __builtin_amdgcn_mfma_f32_16x16x32_f16(a0, bf, acc[0][n], 0, 0, 0);
        acc[1][n] = __builtin_amdgcn_mfma_f32_16x16x32_f16(a1, bf, acc[1][n], 0, 0, 0);
      }
    }
    __syncthreads();
  }

  // ---- softmax over KL (cross-wave) ----
  float xlv[2][4], xmv[2][4];
#pragma unroll
  for (int m = 0; m < 2; ++m)
#pragma unroll
    for (int q = 0; q < 4; ++q) {
      int row = m * 16 + l4 * 4 + q;
      xlv[m][q] = xlog[(size_t)b * XL_ + x0 + row];
      xmv[m][q] = x_mask[(size_t)b * XL_ + x0 + row];
    }
  float klv[8], kmv[8];
#pragma unroll
  for (int n = 0; n < 8; ++n) {
    int kc = wv * 128 + n * 16 + l15;
    klv[n] = klog[(size_t)b * KL_ + kc];
    kmv[n] = key_mask[(size_t)b * KL_ + kc];
  }
  float mxsm[2][4], mxs2[2][4];
#pragma unroll
  for (int m = 0; m < 2; ++m)
#pragma unroll
    for (int q = 0; q < 4; ++q) { mxsm[m][q] = -3.0e38f; mxs2[m][q] = -3.0e38f; }
#pragma unroll
  for (int m = 0; m < 2; ++m)
#pragma unroll
    for (int n = 0; n < 8; ++n)
#pragma unroll
      for (int q = 0; q < 4; ++q) {
        float s = acc[m][n][q] + xlv[m][q] + klv[n];
        float sm = s + (1.f - xmv[m][q] * kmv[n]) * NEGC;
        float s2 = s * kmv[n] + (1.f - kmv[n]) * NEGC;
        mxsm[m][q] = fmaxf(mxsm[m][q], sm);
        mxs2[m][q] = fmaxf(mxs2[m][q], s2);
      }
#pragma unroll
  for (int sh = 8; sh >= 1; sh >>= 1)
#pragma unroll
    for (int m = 0; m < 2; ++m)
#pragma unroll
      for (int q = 0; q < 4; ++q) {
        mxsm[m][q] = fmaxf(mxsm[m][q], __shfl_xor(mxsm[m][q], sh));
        mxs2[m][q] = fmaxf(mxs2[m][q], __shfl_xor(mxs2[m][q], sh));
      }
  if (l15 == 0) {
#pragma unroll
    for (int m = 0; m < 2; ++m)
#pragma unroll
      for (int q = 0; q < 4; ++q) {
        int row = m * 16 + l4 * 4 + q;
        redA[wv][row] = mxsm[m][q];
        redB[wv][row] = mxs2[m][q];
      }
  }
  __syncthreads();
  float gmx[2][4];
#pragma unroll
  for (int m = 0; m < 2; ++m)
#pragma unroll
    for (int q = 0; q < 4; ++q) {
      int row = m * 16 + l4 * 4 + q;
      gmx[m][q] = fmaxf(fmaxf(redA[0][row], redA[1][row]),
                        fmaxf(redA[2][row], redA[3][row]));
    }
  if (tid < 32) {
    float v = fmaxf(fmaxf(redB[0][tid], redB[1][tid]),
                    fmaxf(redB[2][tid], redB[3][tid]));
    maxs[(size_t)b * XL_ + x0 + tid] = v;
  }
  // exp pass: write P (unnormalized, fp16, swizzled), accumulate row sums
  float rs[2][4];
#pragma unroll
  for (int m = 0; m < 2; ++m)
#pragma unroll
    for (int q = 0; q < 4; ++q) rs[m][q] = 0.f;
#pragma unroll
  for (int m = 0; m < 2; ++m)
#pragma unroll
    for (int n = 0; n < 8; ++n)
#pragma unroll
      for (int q = 0; q < 4; ++q) {
        int row = m * 16 + l4 * 4 + q;
        int col = wv * 128 + n * 16 + l15;
        float s = acc[m][n][q] + xlv[m][q] + klv[n];
        float sm = s + (1.f - xmv[m][q] * kmv[n]) * NEGC;
        float e = __expf(sm - gmx[m][q]);
        rs[m][q] += e;
        int chs = (col >> 3) ^ (row & 7);
        *((unsigned short*)((char*)Pt + row * 1024 + chs * 16 + (col & 7) * 2)) = f2h(e);
      }
#pragma unroll
  for (int sh = 8; sh >= 1; sh >>= 1)
#pragma unroll
    for (int m = 0; m < 2; ++m)
#pragma unroll
      for (int q = 0; q < 4; ++q) rs[m][q] += __shfl_xor(rs[m][q], sh);
  if (l15 == 0) {
#pragma unroll
    for (int m = 0; m < 2; ++m)
#pragma unroll
      for (int q = 0; q < 4; ++q) redC[wv][m * 16 + l4 * 4 + q] = rs[m][q];
  }
  __syncthreads();

  // ---- phase 2: PV ----
  float dn[2][4];
#pragma unroll
  for (int m = 0; m < 2; ++m)
#pragma unroll
    for (int q = 0; q < 4; ++q) {
      int row = m * 16 + l4 * 4 + q;
      dn[m][q] = 1.f / (redC[0][row] + redC[1][row] + redC[2][row] + redC[3][row]);
    }
  const unsigned short* KhTB = KhT + (size_t)b * D_ * KL_;
  size_t obase0 = ((size_t)b * XL_ + x0) * (size_t)(4 * D_);
  const int rs7 = l15 & 7;
  for (int sc = 0; sc < 4; ++sc) {
    int c0 = wv * 256 + sc * 64;
    f32x4 acc2[2][4];
#pragma unroll
    for (int m = 0; m < 2; ++m)
#pragma unroll
      for (int n = 0; n < 4; ++n) { f32x4 z = {0.f, 0.f, 0.f, 0.f}; acc2[m][n] = z; }
    const unsigned short* tp[4];
#pragma unroll
    for (int n = 0; n < 4; ++n)
      tp[n] = KhTB + (size_t)(c0 + n * 16 + l15) * KL_ + l4 * 8;
    for (int kk = 0; kk < KL_; kk += 32) {
      int cb = kk >> 3;
      f16x8 a0 = *(const f16x8*)((char*)Pt + l15 * 1024 + (((cb + l4) ^ rs7) * 16));
      f16x8 a1 = *(const f16x8*)((char*)Pt + (16 + l15) * 1024 + (((cb + l4) ^ rs7) * 16));
#pragma unroll
      for (int n = 0; n < 4; ++n) {
        f16x8 bb = *(const f16x8*)(tp[n] + kk);
        acc2[0][n] = __builtin_amdgcn_mfma_f32_16x16x32_f16(a0, bb, acc2[0][n], 0, 0, 0);
        acc2[1][n] = __builtin_amdgcn_mfma_f32_16x16x32_f16(a1, bb, acc2[1][n], 0, 0, 0);
      }
    }
#pragma unroll
    for (int m = 0; m < 2; ++m)
#pragma unroll
      for (int n = 0; n < 4; ++n)
#pragma unroll
        for (int q = 0; q < 4; ++q) {
          int row = m * 16 + l4 * 4 + q;
          int col = c0 + n * 16 + l15;
          float v = acc2[m][n][q] * dn[m][q];
          float xv = xB[(size_t)row * D_ + col];
          size_t ob = obase0 + (size_t)row * (4 * D_);
          out[ob + D_ + col] = v;
          out[ob + 2 * D_ + col] = xv * v;
        }
  }
}

// ---------- p = normalized softmax(max_s * x_mask) * x_mask, per batch ----------
__global__ __launch_bounds__(256) void k_p(const float* __restrict__ maxs,
    const float* __restrict__ x_mask, float* __restrict__ pbuf) {
  int b = blockIdx.x, tid = threadIdx.x;
  int wv = tid >> 6, lane = tid & 63;
  __shared__ float r1[4], r2[4], r3[4];
  const float* ms = maxs + (size_t)b * XL_;
  const float* xm = x_mask + (size_t)b * XL_;
  float tv[4], xmv[4];
  float vmax = -3.0e38f;
#pragma unroll
  for (int i = 0; i < 4; ++i) {
    int xi = i * 256 + tid;
    xmv[i] = xm[xi];
    tv[i] = ms[xi] * xmv[i];
    vmax = fmaxf(vmax, tv[i]);
  }
#pragma unroll
  for (int sh = 32; sh >= 1; sh >>= 1) vmax = fmaxf(vmax, __shfl_xor(vmax, sh));
  if (lane == 0) r1[wv] = vmax;
  __syncthreads();
  float gmax = fmaxf(fmaxf(r1[0], r1[1]), fmaxf(r1[2], r1[3]));
  float e[4]; float es = 0.f;
#pragma unroll
  for (int i = 0; i < 4; ++i) { e[i] = __expf(tv[i] - gmax); es += e[i]; }
#pragma unroll
  for (int sh = 32; sh >= 1; sh >>= 1) es += __shfl_xor(es, sh);
  if (lane == 0) r2[wv] = es;
  __syncthreads();
  float gsum = r2[0] + r2[1] + r2[2] + r2[3];
  float pv[4]; float ps = 0.f;
#pragma unroll
  for (int i = 0; i < 4; ++i) { pv[i] = e[i] / gsum * xmv[i]; ps += pv[i]; }
#pragma unroll
  for (int sh = 32; sh >= 1; sh >>= 1) ps += __shfl_xor(ps, sh);
  if (lane == 0) r3[wv] = ps;
  __syncthreads();
  float gps = r3[0] + r3[1] + r3[2] + r3[3];
  float inv = 1.f / (gps + 1e-13f);
#pragma unroll
  for (int i = 0; i < 4; ++i) pbuf[(size_t)b * XL_ + i * 256 + tid] = pv[i] * inv;
}

// ---------- key2x[b][d] = sum_x p[b][x] * x[b][x][d] ----------
__global__ __launch_bounds__(256) void k_key2x(const float* __restrict__ x,
    const float* __restrict__ pbuf, float* __restrict__ k2x) {
  int b = blockIdx.x >> 2;
  int d0 = (blockIdx.x & 3) * 256;
  __shared__ float ps[XL_];
  for (int i = threadIdx.x; i < XL_; i += 256) ps[i] = pbuf[(size_t)b * XL_ + i];
  __syncthreads();
  const float* xb = x + (size_t)b * XL_ * D_ + d0 + threadIdx.x;
  float acc = 0.f;
#pragma unroll 4
  for (int xi = 0; xi < XL_; ++xi) acc += ps[xi] * xb[(size_t)xi * D_];
  k2x[b * D_ + d0 + threadIdx.x] = acc;
}

// ---------- out[.,0:D)=x ; out[.,3D:4D)=x*key2x ----------
__global__ __launch_bounds__(256) void k_outfinal(const float* __restrict__ x,
    const float* __restrict__ k2x, float* __restrict__ out) {
  size_t t = (size_t)blockIdx.x * 256 + threadIdx.x;
  size_t base = t * 4;
  int b = (int)(base >> 20);
  int rem = (int)(base & ((1u << 20) - 1));
  int xr = rem >> 10;
  int d = rem & 1023;
  float4 xv = *(const float4*)(x + base);
  float4 kv = *(const float4*)(k2x + (size_t)b * D_ + d);
  float* orow = out + ((size_t)b * XL_ + xr) * (size_t)(4 * D_);
  *(float4*)(orow + d) = xv;
  float4 pr;
  pr.x = xv.x * kv.x; pr.y = xv.y * kv.y; pr.z = xv.z * kv.z; pr.w = xv.w * kv.w;
  *(float4*)(orow + 3 * D_ + d) = pr;
}

extern "C" void kernel_launch(void* const* d_in, const int* in_sizes, int n_in,
                              void* d_out, int out_size, void* d_ws, size_t ws_size,
                              hipStream_t stream) {
  (void)in_sizes; (void)n_in; (void)out_size; (void)ws_size;
  const float* x        = (const float*)d_in[0];
  const float* x_mask   = (const float*)d_in[1];
  const float* key      = (const float*)d_in[2];
  const float* key_mask = (const float*)d_in[3];
  const float* w_input  = (const float*)d_in[4];
  const float* w_key    = (const float*)d_in[5];
  const float* dot_w    = (const float*)d_in[6];
  float* out = (float*)d_out;
  char* ws = (char*)d_ws;

  unsigned short* Kh  = (unsigned short*)ws;                        // 16 MB
  unsigned short* KhT = (unsigned short*)(ws + (16u << 20));        // 16 MB
  float* xlog = (float*)(ws + (32u << 20));                         // 64 KB
  float* klog = xlog + B_ * XL_;                                    // 32 KB
  float* maxs = klog + B_ * KL_;                                    // 64 KB
  float* pbuf = maxs + B_ * XL_;                                    // 64 KB
  float* k2x  = pbuf + B_ * XL_;                                    // 64 KB

  k_prep_key<<<dim3(B_ * KL_ / 4), dim3(256), 0, stream>>>(key, w_key, Kh, klog);
  k_prep_x<<<dim3(B_ * XL_ / 4), dim3(256), 0, stream>>>(x, w_input, xlog);
  k_transpose<<<dim3(B_ * 128), dim3(256), 0, stream>>>(Kh, KhT);
  k_attn<<<dim3(512), dim3(256), 0, stream>>>(x, x_mask, key_mask, dot_w,
                                              Kh, KhT, xlog, klog, maxs, out);
  k_p<<<dim3(B_), dim3(256), 0, stream>>>(maxs, x_mask, pbuf);
  k_key2x<<<dim3(B_ * 4), dim3(256), 0, stream>>>(x, pbuf, k2x);
  k_outfinal<<<dim3(B_ * XL_ * D_ / 1024), dim3(256), 0, stream>>>(x, k2x, out);
}

// Round 2
// 245.080 us; speedup vs baseline: 1.9617x; 1.9617x over previous
//
#include <hip/hip_runtime.h>
#include <hip/hip_fp16.h>

#define B_ 16
#define XL_ 1024
#define KL_ 512
#define D_ 1024
#define NEGC (-10000000.0f)

typedef _Float16 f16x8 __attribute__((ext_vector_type(8)));
typedef float f32x4 __attribute__((ext_vector_type(4)));
typedef unsigned short u16x8 __attribute__((ext_vector_type(8)));
typedef unsigned short u16x4 __attribute__((ext_vector_type(4)));

__device__ __forceinline__ unsigned short f2h(float f) {
  __half h = __float2half(f);
  return __half_as_ushort(h);
}

// ---------- prep: x_logits = x . w_input (wave per row) ----------
__global__ __launch_bounds__(256) void k_prep_x(const float* __restrict__ x,
    const float* __restrict__ w_input, float* __restrict__ xlog) {
  int wv = threadIdx.x >> 6, lane = threadIdx.x & 63;
  int row = blockIdx.x * 4 + wv;
  const float* src = x + (size_t)row * D_;
  float acc = 0.f;
#pragma unroll
  for (int j = 0; j < 4; ++j) {
    int d = j * 256 + lane * 4;
    float4 v = *(const float4*)(src + d);
    float4 w = *(const float4*)(w_input + d);
    acc += v.x * w.x + v.y * w.y + v.z * w.z + v.w * w.w;
  }
#pragma unroll
  for (int sh = 32; sh >= 1; sh >>= 1) acc += __shfl_xor(acc, sh);
  if (lane == 0) xlog[row] = acc;
}

// ---------- prep: key -> fp16 Kh, key_logits = key . w_key ----------
__global__ __launch_bounds__(256) void k_prep_key(const float* __restrict__ key,
    const float* __restrict__ w_key, unsigned short* __restrict__ Kh,
    float* __restrict__ klog) {
  int wv = threadIdx.x >> 6, lane = threadIdx.x & 63;
  int row = blockIdx.x * 4 + wv;
  const float* src = key + (size_t)row * D_;
  unsigned short* dst = Kh + (size_t)row * D_;
  float acc = 0.f;
#pragma unroll
  for (int j = 0; j < 4; ++j) {
    int d = j * 256 + lane * 4;
    float4 v = *(const float4*)(src + d);
    float4 w = *(const float4*)(w_key + d);
    acc += v.x * w.x + v.y * w.y + v.z * w.z + v.w * w.w;
    u16x4 hv;
    hv[0] = f2h(v.x); hv[1] = f2h(v.y); hv[2] = f2h(v.z); hv[3] = f2h(v.w);
    *(u16x4*)(dst + d) = hv;
  }
#pragma unroll
  for (int sh = 32; sh >= 1; sh >>= 1) acc += __shfl_xor(acc, sh);
  if (lane == 0) klog[row] = acc;
}

// ---------- transpose Kh [b][k][d] -> KhT [b][d][k] (64x64 tiles) ----------
__global__ __launch_bounds__(256) void k_transpose(const unsigned short* __restrict__ Kh,
    unsigned short* __restrict__ KhT) {
  __shared__ unsigned short tile[64][72];
  int bid = blockIdx.x;
  int b = bid >> 7; int rem = bid & 127; int kt = rem >> 4; int dt = rem & 15;
  const unsigned short* src = Kh + ((size_t)b * KL_ + kt * 64) * D_ + dt * 64;
  int tr = threadIdx.x >> 3, tc = (threadIdx.x & 7) * 8;
#pragma unroll
  for (int i = 0; i < 2; ++i) {
    int r = i * 32 + tr;
    u16x8 v = *(const u16x8*)(src + (size_t)r * D_ + tc);
    *(u16x8*)(&tile[r][tc]) = v;
  }
  __syncthreads();
  unsigned short* dst = KhT + ((size_t)b * D_ + dt * 64) * KL_ + kt * 64;
#pragma unroll
  for (int i = 0; i < 2; ++i) {
    int dr = i * 32 + tr;
    u16x8 v;
#pragma unroll
    for (int j = 0; j < 8; ++j) v[j] = tile[tc + j][dr];
    *(u16x8*)(dst + (size_t)dr * KL_ + tc) = v;
  }
}

// ---------- main attention kernel ----------
// 512 thr (8 waves), 32 x-rows x KL=512 per block, grid 512 (2 blocks/CU).
// Stage ALL of Q [32x1024] fp16 (XOR chunk-swizzle) once -> barrier-free QK^T.
// Wave w owns S-cols w*64..+64 in QK^T and out-cols w*128..+128 in PV.
// LDS: Qall 64KB; after QK^T, region is reused for P tile (32KB) + red arrays.
__global__ __launch_bounds__(512, 4) void k_attn(
    const float* __restrict__ x, const float* __restrict__ x_mask,
    const float* __restrict__ key_mask, const float* __restrict__ dot_w,
    const unsigned short* __restrict__ Kh, const unsigned short* __restrict__ KhT,
    const float* __restrict__ xlog, const float* __restrict__ klog,
    float* __restrict__ maxs, float* __restrict__ out) {
  __shared__ unsigned short Qall[32 * 1024];        // 64KB exactly
  unsigned short* Pt = Qall;                        // alias: 32KB P tile (PV phase)
  float* redA = (float*)(Qall + 16384);             // alias: bytes 32768+ (post-QK^T)
  float* redB = redA + 8 * 32;
  float* redC = redB + 8 * 32;

  const int tid = threadIdx.x;
  const int wv = tid >> 6;               // 0..7
  const int lane = tid & 63;
  const int l15 = lane & 15, l4 = lane >> 4;
  const int r7 = l15 & 7;

  int bid = blockIdx.x;
  int b = (bid & 7) * 2 + (bid >> 8);
  int x0 = ((bid >> 3) & 31) * 32;

  const unsigned short* KhB = Kh + (size_t)b * KL_ * D_;
  const float* xB = x + ((size_t)b * XL_ + x0) * D_;

  // ---- stage Q = fp16(x * dot_w), [32][1024], 16B-chunk XOR swizzle ----
  {
    int row = tid >> 4;                  // 0..31
    int cg = tid & 15;
    const float* sp = xB + (size_t)row * D_;
    char* qrow = (char*)Qall + row * 2048;
    int rsw = row & 7;
#pragma unroll
    for (int j = 0; j < 16; ++j) {
      int c4 = cg + j * 16;              // float4 index 0..255
      float4 v = *(const float4*)(sp + c4 * 4);
      float4 w = *(const float4*)(dot_w + c4 * 4);
      u16x4 hv;
      hv[0] = f2h(v.x * w.x); hv[1] = f2h(v.y * w.y);
      hv[2] = f2h(v.z * w.z); hv[3] = f2h(v.w * w.w);
      *(u16x4*)(qrow + (((c4 >> 1) ^ rsw) << 4) + ((c4 & 1) << 3)) = hv;
    }
  }
  __syncthreads();

  // ---- QK^T: barrier-free MFMA loop over D ----
  f32x4 acc[2][4];
#pragma unroll
  for (int m = 0; m < 2; ++m)
#pragma unroll
    for (int n = 0; n < 4; ++n) { f32x4 z = {0.f, 0.f, 0.f, 0.f}; acc[m][n] = z; }

  const unsigned short* bp[4];
#pragma unroll
  for (int n = 0; n < 4; ++n)
    bp[n] = KhB + (size_t)(wv * 64 + n * 16 + l15) * D_ + l4 * 8;
  const char* qa0 = (char*)Qall + l15 * 2048;
  const char* qa1 = (char*)Qall + (16 + l15) * 2048;

#pragma unroll 2
  for (int dk = 0; dk < D_; dk += 32) {
    f16x8 b0 = *(const f16x8*)(bp[0] + dk);
    f16x8 b1 = *(const f16x8*)(bp[1] + dk);
    f16x8 b2 = *(const f16x8*)(bp[2] + dk);
    f16x8 b3 = *(const f16x8*)(bp[3] + dk);
    int c = (((dk >> 3) + l4) ^ r7) << 4;
    f16x8 a0 = *(const f16x8*)(qa0 + c);
    f16x8 a1 = *(const f16x8*)(qa1 + c);
    __builtin_amdgcn_s_setprio(1);
    acc[0][0] = __builtin_amdgcn_mfma_f32_16x16x32_f16(a0, b0, acc[0][0], 0, 0, 0);
    acc[1][0] = __builtin_amdgcn_mfma_f32_16x16x32_f16(a1, b0, acc[1][0], 0, 0, 0);
    acc[0][1] = __builtin_amdgcn_mfma_f32_16x16x32_f16(a0, b1, acc[0][1], 0, 0, 0);
    acc[1][1] = __builtin_amdgcn_mfma_f32_16x16x32_f16(a1, b1, acc[1][1], 0, 0, 0);
    acc[0][2] = __builtin_amdgcn_mfma_f32_16x16x32_f16(a0, b2, acc[0][2], 0, 0, 0);
    acc[1][2] = __builtin_amdgcn_mfma_f32_16x16x32_f16(a1, b2, acc[1][2], 0, 0, 0);
    acc[0][3] = __builtin_amdgcn_mfma_f32_16x16x32_f16(a0, b3, acc[0][3], 0, 0, 0);
    acc[1][3] = __builtin_amdgcn_mfma_f32_16x16x32_f16(a1, b3, acc[1][3], 0, 0, 0);
    __builtin_amdgcn_s_setprio(0);
  }
  __syncthreads();   // Q region dead beyond this point (red arrays alias it)

  // ---- softmax over KL (cross-wave via LDS) ----
  float xlv[2][4], xmv[2][4];
#pragma unroll
  for (int m = 0; m < 2; ++m)
#pragma unroll
    for (int q = 0; q < 4; ++q) {
      int row = m * 16 + l4 * 4 + q;
      xlv[m][q] = xlog[(size_t)b * XL_ + x0 + row];
      xmv[m][q] = x_mask[(size_t)b * XL_ + x0 + row];
    }
  float klv[4], kmv[4];
#pragma unroll
  for (int n = 0; n < 4; ++n) {
    int kc = wv * 64 + n * 16 + l15;
    klv[n] = klog[(size_t)b * KL_ + kc];
    kmv[n] = key_mask[(size_t)b * KL_ + kc];
  }
  float mxsm[2][4], mxs2[2][4];
#pragma unroll
  for (int m = 0; m < 2; ++m)
#pragma unroll
    for (int q = 0; q < 4; ++q) { mxsm[m][q] = -3.0e38f; mxs2[m][q] = -3.0e38f; }
#pragma unroll
  for (int m = 0; m < 2; ++m)
#pragma unroll
    for (int n = 0; n < 4; ++n)
#pragma unroll
      for (int q = 0; q < 4; ++q) {
        float s = acc[m][n][q] + xlv[m][q] + klv[n];
        float sm = s + (1.f - xmv[m][q] * kmv[n]) * NEGC;
        float s2 = s * kmv[n] + (1.f - kmv[n]) * NEGC;
        mxsm[m][q] = fmaxf(mxsm[m][q], sm);
        mxs2[m][q] = fmaxf(mxs2[m][q], s2);
      }
#pragma unroll
  for (int sh = 8; sh >= 1; sh >>= 1)
#pragma unroll
    for (int m = 0; m < 2; ++m)
#pragma unroll
      for (int q = 0; q < 4; ++q) {
        mxsm[m][q] = fmaxf(mxsm[m][q], __shfl_xor(mxsm[m][q], sh));
        mxs2[m][q] = fmaxf(mxs2[m][q], __shfl_xor(mxs2[m][q], sh));
      }
  if (l15 == 0) {
#pragma unroll
    for (int m = 0; m < 2; ++m)
#pragma unroll
      for (int q = 0; q < 4; ++q) {
        int row = m * 16 + l4 * 4 + q;
        redA[wv * 32 + row] = mxsm[m][q];
        redB[wv * 32 + row] = mxs2[m][q];
      }
  }
  __syncthreads();
  float gmx[2][4];
#pragma unroll
  for (int m = 0; m < 2; ++m)
#pragma unroll
    for (int q = 0; q < 4; ++q) {
      int row = m * 16 + l4 * 4 + q;
      float v = redA[row];
#pragma unroll
      for (int w = 1; w < 8; ++w) v = fmaxf(v, redA[w * 32 + row]);
      gmx[m][q] = v;
    }
  if (tid < 32) {
    float v = redB[tid];
#pragma unroll
    for (int w = 1; w < 8; ++w) v = fmaxf(v, redB[w * 32 + tid]);
    maxs[(size_t)b * XL_ + x0 + tid] = v;
  }
  // exp pass: write P (unnormalized fp16, swizzled) into aliased region, row sums
  float rs[2][4];
#pragma unroll
  for (int m = 0; m < 2; ++m)
#pragma unroll
    for (int q = 0; q < 4; ++q) rs[m][q] = 0.f;
#pragma unroll
  for (int m = 0; m < 2; ++m)
#pragma unroll
    for (int n = 0; n < 4; ++n)
#pragma unroll
      for (int q = 0; q < 4; ++q) {
        int row = m * 16 + l4 * 4 + q;
        int col = wv * 64 + n * 16 + l15;
        float s = acc[m][n][q] + xlv[m][q] + klv[n];
        float sm = s + (1.f - xmv[m][q] * kmv[n]) * NEGC;
        float e = __expf(sm - gmx[m][q]);
        rs[m][q] += e;
        int chs = (col >> 3) ^ (row & 7);
        *((unsigned short*)((char*)Pt + row * 1024 + chs * 16 + (col & 7) * 2)) = f2h(e);
      }
#pragma unroll
  for (int sh = 8; sh >= 1; sh >>= 1)
#pragma unroll
    for (int m = 0; m < 2; ++m)
#pragma unroll
      for (int q = 0; q < 4; ++q) rs[m][q] += __shfl_xor(rs[m][q], sh);
  if (l15 == 0) {
#pragma unroll
    for (int m = 0; m < 2; ++m)
#pragma unroll
      for (int q = 0; q < 4; ++q) redC[wv * 32 + m * 16 + l4 * 4 + q] = rs[m][q];
  }
  __syncthreads();

  // ---- PV: wave owns 128 out-cols; barrier-free ----
  float dn[2][4];
#pragma unroll
  for (int m = 0; m < 2; ++m)
#pragma unroll
    for (int q = 0; q < 4; ++q) {
      int row = m * 16 + l4 * 4 + q;
      float sum = redC[row];
#pragma unroll
      for (int w = 1; w < 8; ++w) sum += redC[w * 32 + row];
      dn[m][q] = 1.f / sum;
    }
  const unsigned short* KhTB = KhT + (size_t)b * D_ * KL_;
  size_t obase0 = ((size_t)b * XL_ + x0) * (size_t)(4 * D_);
  const char* pa0 = (char*)Pt + l15 * 1024;
  const char* pa1 = (char*)Pt + (16 + l15) * 1024;
#pragma unroll
  for (int sc = 0; sc < 2; ++sc) {
    int c0 = wv * 128 + sc * 64;
    f32x4 acc2[2][4];
#pragma unroll
    for (int m = 0; m < 2; ++m)
#pragma unroll
      for (int n = 0; n < 4; ++n) { f32x4 z = {0.f, 0.f, 0.f, 0.f}; acc2[m][n] = z; }
    const unsigned short* tp[4];
#pragma unroll
    for (int n = 0; n < 4; ++n)
      tp[n] = KhTB + (size_t)(c0 + n * 16 + l15) * KL_ + l4 * 8;
#pragma unroll 2
    for (int kk = 0; kk < KL_; kk += 32) {
      f16x8 b0 = *(const f16x8*)(tp[0] + kk);
      f16x8 b1 = *(const f16x8*)(tp[1] + kk);
      f16x8 b2 = *(const f16x8*)(tp[2] + kk);
      f16x8 b3 = *(const f16x8*)(tp[3] + kk);
      int c = ((((kk >> 3) + l4) ^ r7) << 4);
      f16x8 a0 = *(const f16x8*)(pa0 + c);
      f16x8 a1 = *(const f16x8*)(pa1 + c);
      __builtin_amdgcn_s_setprio(1);
      acc2[0][0] = __builtin_amdgcn_mfma_f32_16x16x32_f16(a0, b0, acc2[0][0], 0, 0, 0);
      acc2[1][0] = __builtin_amdgcn_mfma_f32_16x16x32_f16(a1, b0, acc2[1][0], 0, 0, 0);
      acc2[0][1] = __builtin_amdgcn_mfma_f32_16x16x32_f16(a0, b1, acc2[0][1], 0, 0, 0);
      acc2[1][1] = __builtin_amdgcn_mfma_f32_16x16x32_f16(a1, b1, acc2[1][1], 0, 0, 0);
      acc2[0][2] = __builtin_amdgcn_mfma_f32_16x16x32_f16(a0, b2, acc2[0][2], 0, 0, 0);
      acc2[1][2] = __builtin_amdgcn_mfma_f32_16x16x32_f16(a1, b2, acc2[1][2], 0, 0, 0);
      acc2[0][3] = __builtin_amdgcn_mfma_f32_16x16x32_f16(a0, b3, acc2[0][3], 0, 0, 0);
      acc2[1][3] = __builtin_amdgcn_mfma_f32_16x16x32_f16(a1, b3, acc2[1][3], 0, 0, 0);
      __builtin_amdgcn_s_setprio(0);
    }
#pragma unroll
    for (int m = 0; m < 2; ++m)
#pragma unroll
      for (int n = 0; n < 4; ++n)
#pragma unroll
        for (int q = 0; q < 4; ++q) {
          int row = m * 16 + l4 * 4 + q;
          int col = c0 + n * 16 + l15;
          float v = acc2[m][n][q] * dn[m][q];
          float xv = xB[(size_t)row * D_ + col];
          size_t ob = obase0 + (size_t)row * (4 * D_);
          out[ob + D_ + col] = v;
          out[ob + 2 * D_ + col] = xv * v;
        }
  }
}

// ---------- p = normalized softmax(max_s * x_mask) * x_mask, per batch ----------
__global__ __launch_bounds__(256) void k_p(const float* __restrict__ maxs,
    const float* __restrict__ x_mask, float* __restrict__ pbuf) {
  int b = blockIdx.x, tid = threadIdx.x;
  int wv = tid >> 6, lane = tid & 63;
  __shared__ float r1[4], r2[4], r3[4];
  const float* ms = maxs + (size_t)b * XL_;
  const float* xm = x_mask + (size_t)b * XL_;
  float tv[4], xmv[4];
  float vmax = -3.0e38f;
#pragma unroll
  for (int i = 0; i < 4; ++i) {
    int xi = i * 256 + tid;
    xmv[i] = xm[xi];
    tv[i] = ms[xi] * xmv[i];
    vmax = fmaxf(vmax, tv[i]);
  }
#pragma unroll
  for (int sh = 32; sh >= 1; sh >>= 1) vmax = fmaxf(vmax, __shfl_xor(vmax, sh));
  if (lane == 0) r1[wv] = vmax;
  __syncthreads();
  float gmax = fmaxf(fmaxf(r1[0], r1[1]), fmaxf(r1[2], r1[3]));
  float e[4]; float es = 0.f;
#pragma unroll
  for (int i = 0; i < 4; ++i) { e[i] = __expf(tv[i] - gmax); es += e[i]; }
#pragma unroll
  for (int sh = 32; sh >= 1; sh >>= 1) es += __shfl_xor(es, sh);
  if (lane == 0) r2[wv] = es;
  __syncthreads();
  float gsum = r2[0] + r2[1] + r2[2] + r2[3];
  float pv[4]; float ps = 0.f;
#pragma unroll
  for (int i = 0; i < 4; ++i) { pv[i] = e[i] / gsum * xmv[i]; ps += pv[i]; }
#pragma unroll
  for (int sh = 32; sh >= 1; sh >>= 1) ps += __shfl_xor(ps, sh);
  if (lane == 0) r3[wv] = ps;
  __syncthreads();
  float gps = r3[0] + r3[1] + r3[2] + r3[3];
  float inv = 1.f / (gps + 1e-13f);
#pragma unroll
  for (int i = 0; i < 4; ++i) pbuf[(size_t)b * XL_ + i * 256 + tid] = pv[i] * inv;
}

// ---------- key2x partials: block (b, xc) sums 64 x-rows ----------
__global__ __launch_bounds__(256) void k_key2x_part(const float* __restrict__ x,
    const float* __restrict__ pbuf, float* __restrict__ partial) {
  int b = blockIdx.x >> 4;
  int xc = blockIdx.x & 15;
  __shared__ float ps[64];
  if (threadIdx.x < 64) ps[threadIdx.x] = pbuf[(size_t)b * XL_ + xc * 64 + threadIdx.x];
  __syncthreads();
  const float* xb = x + ((size_t)b * XL_ + xc * 64) * D_;
  float acc0 = 0.f, acc1 = 0.f, acc2 = 0.f, acc3 = 0.f;
  int d = threadIdx.x;
  for (int xi = 0; xi < 64; ++xi) {
    float pv = ps[xi];
    const float* rp = xb + (size_t)xi * D_;
    acc0 += pv * rp[d];
    acc1 += pv * rp[d + 256];
    acc2 += pv * rp[d + 512];
    acc3 += pv * rp[d + 768];
  }
  float* pp = partial + (size_t)blockIdx.x * D_;
  pp[d] = acc0; pp[d + 256] = acc1; pp[d + 512] = acc2; pp[d + 768] = acc3;
}

// ---------- key2x reduce: k2x[b][d] = sum_xc partial ----------
__global__ __launch_bounds__(256) void k_key2x_red(const float* __restrict__ partial,
    float* __restrict__ k2x) {
  int idx = blockIdx.x * 256 + threadIdx.x;
  int b = idx >> 10;
  float s = 0.f;
#pragma unroll
  for (int xc = 0; xc < 16; ++xc)
    s += partial[((size_t)b * 16 + xc) * D_ + (idx & 1023)];
  k2x[idx] = s;
}

// ---------- out[.,0:D)=x ; out[.,3D:4D)=x*key2x ----------
__global__ __launch_bounds__(256) void k_outfinal(const float* __restrict__ x,
    const float* __restrict__ k2x, float* __restrict__ out) {
  size_t t = (size_t)blockIdx.x * 256 + threadIdx.x;
  size_t base = t * 4;
  int b = (int)(base >> 20);
  int rem = (int)(base & ((1u << 20) - 1));
  int xr = rem >> 10;
  int d = rem & 1023;
  float4 xv = *(const float4*)(x + base);
  float4 kv = *(const float4*)(k2x + (size_t)b * D_ + d);
  float* orow = out + ((size_t)b * XL_ + xr) * (size_t)(4 * D_);
  *(float4*)(orow + d) = xv;
  float4 pr;
  pr.x = xv.x * kv.x; pr.y = xv.y * kv.y; pr.z = xv.z * kv.z; pr.w = xv.w * kv.w;
  *(float4*)(orow + 3 * D_ + d) = pr;
}

extern "C" void kernel_launch(void* const* d_in, const int* in_sizes, int n_in,
                              void* d_out, int out_size, void* d_ws, size_t ws_size,
                              hipStream_t stream) {
  (void)in_sizes; (void)n_in; (void)out_size; (void)ws_size;
  const float* x        = (const float*)d_in[0];
  const float* x_mask   = (const float*)d_in[1];
  const float* key      = (const float*)d_in[2];
  const float* key_mask = (const float*)d_in[3];
  const float* w_input  = (const float*)d_in[4];
  const float* w_key    = (const float*)d_in[5];
  const float* dot_w    = (const float*)d_in[6];
  float* out = (float*)d_out;
  char* ws = (char*)d_ws;

  unsigned short* Kh  = (unsigned short*)ws;                        // 16 MB
  unsigned short* KhT = (unsigned short*)(ws + (16u << 20));        // 16 MB
  float* xlog = (float*)(ws + (32u << 20));                         // 64 KB
  float* klog = xlog + B_ * XL_;                                    // 32 KB
  float* maxs = klog + B_ * KL_;                                    // 64 KB
  float* pbuf = maxs + B_ * XL_;                                    // 64 KB
  float* k2x  = pbuf + B_ * XL_;                                    // 64 KB
  float* partial = (float*)ws;   // 1 MB, aliases Kh (dead after k_attn)

  k_prep_key<<<dim3(B_ * KL_ / 4), dim3(256), 0, stream>>>(key, w_key, Kh, klog);
  k_prep_x<<<dim3(B_ * XL_ / 4), dim3(256), 0, stream>>>(x, w_input, xlog);
  k_transpose<<<dim3(B_ * 128), dim3(256), 0, stream>>>(Kh, KhT);
  k_attn<<<dim3(512), dim3(512), 0, stream>>>(x, x_mask, key_mask, dot_w,
                                              Kh, KhT, xlog, klog, maxs, out);
  k_p<<<dim3(B_), dim3(256), 0, stream>>>(maxs, x_mask, pbuf);
  k_key2x_part<<<dim3(B_ * 16), dim3(256), 0, stream>>>(x, pbuf, partial);
  k_key2x_red<<<dim3(B_ * D_ / 256), dim3(256), 0, stream>>>(partial, k2x);
  k_outfinal<<<dim3(B_ * XL_ * D_ / 1024), dim3(256), 0, stream>>>(x, k2x, out);
}

// Round 3
// 233.685 us; speedup vs baseline: 2.0574x; 1.0488x over previous
//
#include <hip/hip_runtime.h>
#include <hip/hip_fp16.h>

#define B_ 16
#define XL_ 1024
#define KL_ 512
#define D_ 1024
#define NEGC (-10000000.0f)

typedef _Float16 f16x8 __attribute__((ext_vector_type(8)));
typedef float f32x4 __attribute__((ext_vector_type(4)));
typedef unsigned short u16x8 __attribute__((ext_vector_type(8)));
typedef unsigned short u16x4 __attribute__((ext_vector_type(4)));

__device__ __forceinline__ unsigned short f2h(float f) {
  __half h = __float2half(f);
  return __half_as_ushort(h);
}

// ---------- prep: x_logits = x . w_input (wave per row) ----------
__global__ __launch_bounds__(256) void k_prep_x(const float* __restrict__ x,
    const float* __restrict__ w_input, float* __restrict__ xlog) {
  int wv = threadIdx.x >> 6, lane = threadIdx.x & 63;
  int row = blockIdx.x * 4 + wv;
  const float* src = x + (size_t)row * D_;
  float acc = 0.f;
#pragma unroll
  for (int j = 0; j < 4; ++j) {
    int d = j * 256 + lane * 4;
    float4 v = *(const float4*)(src + d);
    float4 w = *(const float4*)(w_input + d);
    acc += v.x * w.x + v.y * w.y + v.z * w.z + v.w * w.w;
  }
#pragma unroll
  for (int sh = 32; sh >= 1; sh >>= 1) acc += __shfl_xor(acc, sh);
  if (lane == 0) xlog[row] = acc;
}

// ---------- prep: key -> fp16 Kh, key_logits = key . w_key ----------
__global__ __launch_bounds__(256) void k_prep_key(const float* __restrict__ key,
    const float* __restrict__ w_key, unsigned short* __restrict__ Kh,
    float* __restrict__ klog) {
  int wv = threadIdx.x >> 6, lane = threadIdx.x & 63;
  int row = blockIdx.x * 4 + wv;
  const float* src = key + (size_t)row * D_;
  unsigned short* dst = Kh + (size_t)row * D_;
  float acc = 0.f;
#pragma unroll
  for (int j = 0; j < 4; ++j) {
    int d = j * 256 + lane * 4;
    float4 v = *(const float4*)(src + d);
    float4 w = *(const float4*)(w_key + d);
    acc += v.x * w.x + v.y * w.y + v.z * w.z + v.w * w.w;
    u16x4 hv;
    hv[0] = f2h(v.x); hv[1] = f2h(v.y); hv[2] = f2h(v.z); hv[3] = f2h(v.w);
    *(u16x4*)(dst + d) = hv;
  }
#pragma unroll
  for (int sh = 32; sh >= 1; sh >>= 1) acc += __shfl_xor(acc, sh);
  if (lane == 0) klog[row] = acc;
}

// ---------- transpose Kh [b][k][d] -> KhT [b][d][k] (64x64 tiles) ----------
__global__ __launch_bounds__(256) void k_transpose(const unsigned short* __restrict__ Kh,
    unsigned short* __restrict__ KhT) {
  __shared__ unsigned short tile[64][72];
  int bid = blockIdx.x;
  int b = bid >> 7; int rem = bid & 127; int kt = rem >> 4; int dt = rem & 15;
  const unsigned short* src = Kh + ((size_t)b * KL_ + kt * 64) * D_ + dt * 64;
  int tr = threadIdx.x >> 3, tc = (threadIdx.x & 7) * 8;
#pragma unroll
  for (int i = 0; i < 2; ++i) {
    int r = i * 32 + tr;
    u16x8 v = *(const u16x8*)(src + (size_t)r * D_ + tc);
    *(u16x8*)(&tile[r][tc]) = v;
  }
  __syncthreads();
  unsigned short* dst = KhT + ((size_t)b * D_ + dt * 64) * KL_ + kt * 64;
#pragma unroll
  for (int i = 0; i < 2; ++i) {
    int dr = i * 32 + tr;
    u16x8 v;
#pragma unroll
    for (int j = 0; j < 8; ++j) v[j] = tile[tc + j][dr];
    *(u16x8*)(dst + (size_t)dr * KL_ + tc) = v;
  }
}

// ---------- main attention kernel ----------
// 512 thr (8 waves), 32 x-rows x KL=512 per block, grid 512 (2 blocks/CU).
// TRANSPOSED mfma (first operand = K/KhT frag): lane's x-row = l15 (fixed),
// reg quad = 4 consecutive k (QK^T) / 4 consecutive d (PV) -> float4 epilogue.
__global__ __launch_bounds__(512, 4) void k_attn(
    const float* __restrict__ x, const float* __restrict__ x_mask,
    const float* __restrict__ key_mask, const float* __restrict__ dot_w,
    const unsigned short* __restrict__ Kh, const unsigned short* __restrict__ KhT,
    const float* __restrict__ xlog, const float* __restrict__ klog,
    float* __restrict__ maxs, float* __restrict__ out) {
  __shared__ unsigned short Qall[32 * 1024];        // 64KB exactly
  unsigned short* Pt = Qall;                        // alias: 32KB P tile (PV phase)
  float* redA = (float*)(Qall + 16384);             // alias: bytes 32768+
  float* redB = redA + 256;
  float* redC = redB + 256;

  const int tid = threadIdx.x;
  const int wv = tid >> 6;               // 0..7
  const int lane = tid & 63;
  const int l15 = lane & 15, l4 = lane >> 4;
  const int r7 = l15 & 7;

  int bid = blockIdx.x;
  int b = (bid & 7) * 2 + (bid >> 8);
  int x0 = ((bid >> 3) & 31) * 32;

  const unsigned short* KhB = Kh + (size_t)b * KL_ * D_;
  const float* xB = x + ((size_t)b * XL_ + x0) * D_;

  // ---- stage Q = fp16(x * dot_w), [32][1024], 16B-chunk XOR swizzle ----
  {
    int row = tid >> 4;                  // 0..31
    int cg = tid & 15;
    const float* sp = xB + (size_t)row * D_;
    char* qrow = (char*)Qall + row * 2048;
    int rsw = row & 7;
#pragma unroll
    for (int j = 0; j < 16; ++j) {
      int c4 = cg + j * 16;              // float4 index 0..255
      float4 v = *(const float4*)(sp + c4 * 4);
      float4 w = *(const float4*)(dot_w + c4 * 4);
      u16x4 hv;
      hv[0] = f2h(v.x * w.x); hv[1] = f2h(v.y * w.y);
      hv[2] = f2h(v.z * w.z); hv[3] = f2h(v.w * w.w);
      *(u16x4*)(qrow + (((c4 >> 1) ^ rsw) << 4) + ((c4 & 1) << 3)) = hv;
    }
  }
  __syncthreads();

  // ---- QK^T (transposed): acc[m][n] = mfma(Kfrag_n, Qfrag_m) ----
  // acc[m][n][q]: x-row = m*16+l15, k = wv*64 + n*16 + l4*4 + q
  f32x4 acc[2][4];
#pragma unroll
  for (int m = 0; m < 2; ++m)
#pragma unroll
    for (int n = 0; n < 4; ++n) { f32x4 z = {0.f, 0.f, 0.f, 0.f}; acc[m][n] = z; }

  const unsigned short* bp[4];
#pragma unroll
  for (int n = 0; n < 4; ++n)
    bp[n] = KhB + (size_t)(wv * 64 + n * 16 + l15) * D_ + l4 * 8;
  const char* qa0 = (char*)Qall + l15 * 2048;
  const char* qa1 = (char*)Qall + (16 + l15) * 2048;

#pragma unroll 2
  for (int dk = 0; dk < D_; dk += 32) {
    f16x8 b0 = *(const f16x8*)(bp[0] + dk);
    f16x8 b1 = *(const f16x8*)(bp[1] + dk);
    f16x8 b2 = *(const f16x8*)(bp[2] + dk);
    f16x8 b3 = *(const f16x8*)(bp[3] + dk);
    int c = (((dk >> 3) + l4) ^ r7) << 4;
    f16x8 a0 = *(const f16x8*)(qa0 + c);
    f16x8 a1 = *(const f16x8*)(qa1 + c);
    __builtin_amdgcn_s_setprio(1);
    acc[0][0] = __builtin_amdgcn_mfma_f32_16x16x32_f16(b0, a0, acc[0][0], 0, 0, 0);
    acc[1][0] = __builtin_amdgcn_mfma_f32_16x16x32_f16(b0, a1, acc[1][0], 0, 0, 0);
    acc[0][1] = __builtin_amdgcn_mfma_f32_16x16x32_f16(b1, a0, acc[0][1], 0, 0, 0);
    acc[1][1] = __builtin_amdgcn_mfma_f32_16x16x32_f16(b1, a1, acc[1][1], 0, 0, 0);
    acc[0][2] = __builtin_amdgcn_mfma_f32_16x16x32_f16(b2, a0, acc[0][2], 0, 0, 0);
    acc[1][2] = __builtin_amdgcn_mfma_f32_16x16x32_f16(b2, a1, acc[1][2], 0, 0, 0);
    acc[0][3] = __builtin_amdgcn_mfma_f32_16x16x32_f16(b3, a0, acc[0][3], 0, 0, 0);
    acc[1][3] = __builtin_amdgcn_mfma_f32_16x16x32_f16(b3, a1, acc[1][3], 0, 0, 0);
    __builtin_amdgcn_s_setprio(0);
  }
  __syncthreads();   // Q region dead beyond this point

  // ---- softmax over KL ----
  float xlv[2], xmv[2];
#pragma unroll
  for (int m = 0; m < 2; ++m) {
    int row = m * 16 + l15;
    xlv[m] = xlog[(size_t)b * XL_ + x0 + row];
    xmv[m] = x_mask[(size_t)b * XL_ + x0 + row];
  }
  f32x4 klv[4], kmv[4];
#pragma unroll
  for (int n = 0; n < 4; ++n) {
    int kb = wv * 64 + n * 16 + l4 * 4;
    klv[n] = *(const f32x4*)(klog + (size_t)b * KL_ + kb);
    kmv[n] = *(const f32x4*)(key_mask + (size_t)b * KL_ + kb);
  }
  float mxsm[2] = {-3.0e38f, -3.0e38f}, mxs2[2] = {-3.0e38f, -3.0e38f};
#pragma unroll
  for (int m = 0; m < 2; ++m)
#pragma unroll
    for (int n = 0; n < 4; ++n)
#pragma unroll
      for (int q = 0; q < 4; ++q) {
        float s = acc[m][n][q] + xlv[m] + klv[n][q];
        float sm = s + (1.f - xmv[m] * kmv[n][q]) * NEGC;
        float s2 = s * kmv[n][q] + (1.f - kmv[n][q]) * NEGC;
        mxsm[m] = fmaxf(mxsm[m], sm);
        mxs2[m] = fmaxf(mxs2[m], s2);
      }
#pragma unroll
  for (int m = 0; m < 2; ++m) {
    mxsm[m] = fmaxf(mxsm[m], __shfl_xor(mxsm[m], 16));
    mxsm[m] = fmaxf(mxsm[m], __shfl_xor(mxsm[m], 32));
    mxs2[m] = fmaxf(mxs2[m], __shfl_xor(mxs2[m], 16));
    mxs2[m] = fmaxf(mxs2[m], __shfl_xor(mxs2[m], 32));
  }
  if (l4 == 0) {
#pragma unroll
    for (int m = 0; m < 2; ++m) {
      redA[wv * 32 + m * 16 + l15] = mxsm[m];
      redB[wv * 32 + m * 16 + l15] = mxs2[m];
    }
  }
  __syncthreads();
  float gmx[2];
#pragma unroll
  for (int m = 0; m < 2; ++m) {
    int row = m * 16 + l15;
    float v = redA[row];
#pragma unroll
    for (int w = 1; w < 8; ++w) v = fmaxf(v, redA[w * 32 + row]);
    gmx[m] = v;
  }
  if (tid < 32) {
    float v = redB[tid];
#pragma unroll
    for (int w = 1; w < 8; ++w) v = fmaxf(v, redB[w * 32 + tid]);
    maxs[(size_t)b * XL_ + x0 + tid] = v;
  }
  // exp pass: P^ written as [x-row][k] fp16, 8B granules, XOR-swizzled
  float rs[2] = {0.f, 0.f};
#pragma unroll
  for (int m = 0; m < 2; ++m) {
    int row = m * 16 + l15;
    char* prow = (char*)Pt + row * 1024;
    int rsw = row & 7;
#pragma unroll
    for (int n = 0; n < 4; ++n) {
      int k = wv * 64 + n * 16 + l4 * 4;
      u16x4 pk;
#pragma unroll
      for (int q = 0; q < 4; ++q) {
        float s = acc[m][n][q] + xlv[m] + klv[n][q];
        float sm = s + (1.f - xmv[m] * kmv[n][q]) * NEGC;
        float e = __expf(sm - gmx[m]);
        rs[m] += e;
        pk[q] = f2h(e);
      }
      *(u16x4*)(prow + ((((k >> 3) ^ rsw) << 4) + ((k & 4) << 1))) = pk;
    }
  }
#pragma unroll
  for (int m = 0; m < 2; ++m) {
    rs[m] += __shfl_xor(rs[m], 16);
    rs[m] += __shfl_xor(rs[m], 32);
  }
  if (l4 == 0) {
#pragma unroll
    for (int m = 0; m < 2; ++m) redC[wv * 32 + m * 16 + l15] = rs[m];
  }
  __syncthreads();

  // ---- PV (transposed): acc2[m][n] = mfma(KhTfrag_n, Pfrag_m) ----
  // acc2[m][n][q]: x-row = m*16+l15, d = c0 + n*16 + l4*4 + q
  float dn[2];
#pragma unroll
  for (int m = 0; m < 2; ++m) {
    int row = m * 16 + l15;
    float sum = redC[row];
#pragma unroll
    for (int w = 1; w < 8; ++w) sum += redC[w * 32 + row];
    dn[m] = 1.f / sum;
  }
  const unsigned short* KhTB = KhT + (size_t)b * D_ * KL_;
  size_t obase0 = ((size_t)b * XL_ + x0) * (size_t)(4 * D_);
  const char* pa0 = (char*)Pt + l15 * 1024;
  const char* pa1 = (char*)Pt + (16 + l15) * 1024;
#pragma unroll
  for (int sc = 0; sc < 2; ++sc) {
    int c0 = wv * 128 + sc * 64;
    f32x4 acc2[2][4];
#pragma unroll
    for (int m = 0; m < 2; ++m)
#pragma unroll
      for (int n = 0; n < 4; ++n) { f32x4 z = {0.f, 0.f, 0.f, 0.f}; acc2[m][n] = z; }
    const unsigned short* tp[4];
#pragma unroll
    for (int n = 0; n < 4; ++n)
      tp[n] = KhTB + (size_t)(c0 + n * 16 + l15) * KL_ + l4 * 8;
#pragma unroll 2
    for (int kk = 0; kk < KL_; kk += 32) {
      f16x8 b0 = *(const f16x8*)(tp[0] + kk);
      f16x8 b1 = *(const f16x8*)(tp[1] + kk);
      f16x8 b2 = *(const f16x8*)(tp[2] + kk);
      f16x8 b3 = *(const f16x8*)(tp[3] + kk);
      int c = ((((kk >> 3) + l4) ^ r7) << 4);
      f16x8 a0 = *(const f16x8*)(pa0 + c);
      f16x8 a1 = *(const f16x8*)(pa1 + c);
      __builtin_amdgcn_s_setprio(1);
      acc2[0][0] = __builtin_amdgcn_mfma_f32_16x16x32_f16(b0, a0, acc2[0][0], 0, 0, 0);
      acc2[1][0] = __builtin_amdgcn_mfma_f32_16x16x32_f16(b0, a1, acc2[1][0], 0, 0, 0);
      acc2[0][1] = __builtin_amdgcn_mfma_f32_16x16x32_f16(b1, a0, acc2[0][1], 0, 0, 0);
      acc2[1][1] = __builtin_amdgcn_mfma_f32_16x16x32_f16(b1, a1, acc2[1][1], 0, 0, 0);
      acc2[0][2] = __builtin_amdgcn_mfma_f32_16x16x32_f16(b2, a0, acc2[0][2], 0, 0, 0);
      acc2[1][2] = __builtin_amdgcn_mfma_f32_16x16x32_f16(b2, a1, acc2[1][2], 0, 0, 0);
      acc2[0][3] = __builtin_amdgcn_mfma_f32_16x16x32_f16(b3, a0, acc2[0][3], 0, 0, 0);
      acc2[1][3] = __builtin_amdgcn_mfma_f32_16x16x32_f16(b3, a1, acc2[1][3], 0, 0, 0);
      __builtin_amdgcn_s_setprio(0);
    }
#pragma unroll
    for (int m = 0; m < 2; ++m) {
      int row = m * 16 + l15;
      size_t ob = obase0 + (size_t)row * (4 * D_);
      const float* xr = xB + (size_t)row * D_;
#pragma unroll
      for (int n = 0; n < 4; ++n) {
        int col = c0 + n * 16 + l4 * 4;
        f32x4 v = acc2[m][n];
        v[0] *= dn[m]; v[1] *= dn[m]; v[2] *= dn[m]; v[3] *= dn[m];
        f32x4 xv = *(const f32x4*)(xr + col);
        *(f32x4*)(out + ob + D_ + col) = v;
        f32x4 pv;
        pv[0] = v[0] * xv[0]; pv[1] = v[1] * xv[1];
        pv[2] = v[2] * xv[2]; pv[3] = v[3] * xv[3];
        *(f32x4*)(out + ob + 2 * D_ + col) = pv;
      }
    }
  }
}

// ---------- p = normalized softmax(max_s * x_mask) * x_mask, per batch ----------
__global__ __launch_bounds__(256) void k_p(const float* __restrict__ maxs,
    const float* __restrict__ x_mask, float* __restrict__ pbuf) {
  int b = blockIdx.x, tid = threadIdx.x;
  int wv = tid >> 6, lane = tid & 63;
  __shared__ float r1[4], r2[4], r3[4];
  const float* ms = maxs + (size_t)b * XL_;
  const float* xm = x_mask + (size_t)b * XL_;
  float tv[4], xmv[4];
  float vmax = -3.0e38f;
#pragma unroll
  for (int i = 0; i < 4; ++i) {
    int xi = i * 256 + tid;
    xmv[i] = xm[xi];
    tv[i] = ms[xi] * xmv[i];
    vmax = fmaxf(vmax, tv[i]);
  }
#pragma unroll
  for (int sh = 32; sh >= 1; sh >>= 1) vmax = fmaxf(vmax, __shfl_xor(vmax, sh));
  if (lane == 0) r1[wv] = vmax;
  __syncthreads();
  float gmax = fmaxf(fmaxf(r1[0], r1[1]), fmaxf(r1[2], r1[3]));
  float e[4]; float es = 0.f;
#pragma unroll
  for (int i = 0; i < 4; ++i) { e[i] = __expf(tv[i] - gmax); es += e[i]; }
#pragma unroll
  for (int sh = 32; sh >= 1; sh >>= 1) es += __shfl_xor(es, sh);
  if (lane == 0) r2[wv] = es;
  __syncthreads();
  float gsum = r2[0] + r2[1] + r2[2] + r2[3];
  float pv[4]; float ps = 0.f;
#pragma unroll
  for (int i = 0; i < 4; ++i) { pv[i] = e[i] / gsum * xmv[i]; ps += pv[i]; }
#pragma unroll
  for (int sh = 32; sh >= 1; sh >>= 1) ps += __shfl_xor(ps, sh);
  if (lane == 0) r3[wv] = ps;
  __syncthreads();
  float gps = r3[0] + r3[1] + r3[2] + r3[3];
  float inv = 1.f / (gps + 1e-13f);
#pragma unroll
  for (int i = 0; i < 4; ++i) pbuf[(size_t)b * XL_ + i * 256 + tid] = pv[i] * inv;
}

// ---------- key2x partials: block (b, xc) sums 64 x-rows ----------
__global__ __launch_bounds__(256) void k_key2x_part(const float* __restrict__ x,
    const float* __restrict__ pbuf, float* __restrict__ partial) {
  int b = blockIdx.x >> 4;
  int xc = blockIdx.x & 15;
  __shared__ float ps[64];
  if (threadIdx.x < 64) ps[threadIdx.x] = pbuf[(size_t)b * XL_ + xc * 64 + threadIdx.x];
  __syncthreads();
  const float* xb = x + ((size_t)b * XL_ + xc * 64) * D_;
  float acc0 = 0.f, acc1 = 0.f, acc2 = 0.f, acc3 = 0.f;
  int d = threadIdx.x;
  for (int xi = 0; xi < 64; ++xi) {
    float pv = ps[xi];
    const float* rp = xb + (size_t)xi * D_;
    acc0 += pv * rp[d];
    acc1 += pv * rp[d + 256];
    acc2 += pv * rp[d + 512];
    acc3 += pv * rp[d + 768];
  }
  float* pp = partial + (size_t)blockIdx.x * D_;
  pp[d] = acc0; pp[d + 256] = acc1; pp[d + 512] = acc2; pp[d + 768] = acc3;
}

// ---------- key2x reduce: k2x[b][d] = sum_xc partial ----------
__global__ __launch_bounds__(256) void k_key2x_red(const float* __restrict__ partial,
    float* __restrict__ k2x) {
  int idx = blockIdx.x * 256 + threadIdx.x;
  int b = idx >> 10;
  float s = 0.f;
#pragma unroll
  for (int xc = 0; xc < 16; ++xc)
    s += partial[((size_t)b * 16 + xc) * D_ + (idx & 1023)];
  k2x[idx] = s;
}

// ---------- out[.,0:D)=x ; out[.,3D:4D)=x*key2x ----------
__global__ __launch_bounds__(256) void k_outfinal(const float* __restrict__ x,
    const float* __restrict__ k2x, float* __restrict__ out) {
  size_t t = (size_t)blockIdx.x * 256 + threadIdx.x;
  size_t base = t * 4;
  int b = (int)(base >> 20);
  int rem = (int)(base & ((1u << 20) - 1));
  int xr = rem >> 10;
  int d = rem & 1023;
  float4 xv = *(const float4*)(x + base);
  float4 kv = *(const float4*)(k2x + (size_t)b * D_ + d);
  float* orow = out + ((size_t)b * XL_ + xr) * (size_t)(4 * D_);
  *(float4*)(orow + d) = xv;
  float4 pr;
  pr.x = xv.x * kv.x; pr.y = xv.y * kv.y; pr.z = xv.z * kv.z; pr.w = xv.w * kv.w;
  *(float4*)(orow + 3 * D_ + d) = pr;
}

extern "C" void kernel_launch(void* const* d_in, const int* in_sizes, int n_in,
                              void* d_out, int out_size, void* d_ws, size_t ws_size,
                              hipStream_t stream) {
  (void)in_sizes; (void)n_in; (void)out_size; (void)ws_size;
  const float* x        = (const float*)d_in[0];
  const float* x_mask   = (const float*)d_in[1];
  const float* key      = (const float*)d_in[2];
  const float* key_mask = (const float*)d_in[3];
  const float* w_input  = (const float*)d_in[4];
  const float* w_key    = (const float*)d_in[5];
  const float* dot_w    = (const float*)d_in[6];
  float* out = (float*)d_out;
  char* ws = (char*)d_ws;

  unsigned short* Kh  = (unsigned short*)ws;                        // 16 MB
  unsigned short* KhT = (unsigned short*)(ws + (16u << 20));        // 16 MB
  float* xlog = (float*)(ws + (32u << 20));                         // 64 KB
  float* klog = xlog + B_ * XL_;                                    // 32 KB
  float* maxs = klog + B_ * KL_;                                    // 64 KB
  float* pbuf = maxs + B_ * XL_;                                    // 64 KB
  float* k2x  = pbuf + B_ * XL_;                                    // 64 KB
  float* partial = (float*)ws;   // 1 MB, aliases Kh (dead after k_attn)

  k_prep_key<<<dim3(B_ * KL_ / 4), dim3(256), 0, stream>>>(key, w_key, Kh, klog);
  k_prep_x<<<dim3(B_ * XL_ / 4), dim3(256), 0, stream>>>(x, w_input, xlog);
  k_transpose<<<dim3(B_ * 128), dim3(256), 0, stream>>>(Kh, KhT);
  k_attn<<<dim3(512), dim3(512), 0, stream>>>(x, x_mask, key_mask, dot_w,
                                              Kh, KhT, xlog, klog, maxs, out);
  k_p<<<dim3(B_), dim3(256), 0, stream>>>(maxs, x_mask, pbuf);
  k_key2x_part<<<dim3(B_ * 16), dim3(256), 0, stream>>>(x, pbuf, partial);
  k_key2x_red<<<dim3(B_ * D_ / 256), dim3(256), 0, stream>>>(partial, k2x);
  k_outfinal<<<dim3(B_ * XL_ * D_ / 1024), dim3(256), 0, stream>>>(x, k2x, out);
}